// Round 4
// baseline (202.454 us; speedup 1.0000x reference)
//
#include <hip/hip_runtime.h>
#include <hip/hip_bf16.h>
#include <cstdint>
#include <cstddef>

#define E_ 1024
#define H_ 16
#define D_ 64
#define B_ 2
#define S_ 2048
#define T_ 4096   // B_*S_
#define NQ_ 3072  // 3*E_

typedef __bf16 bf16_t;
typedef bf16_t bf16x8 __attribute__((ext_vector_type(8)));
typedef float f32x4 __attribute__((ext_vector_type(4)));

static __device__ __forceinline__ unsigned short f2bf(float f) {
    __hip_bfloat16 h = __float2bfloat16(f);
    return __builtin_bit_cast(unsigned short, h);
}
static __device__ __forceinline__ unsigned pack2(float a, float b) {
    return (unsigned)f2bf(a) | ((unsigned)f2bf(b) << 16);
}
// HW packed f32->bf16 (RNE), 1 instruction. T12 recipe (no builtin on gfx950).
static __device__ __forceinline__ unsigned cvt_pk(float a, float b) {
    unsigned r;
    asm("v_cvt_pk_bf16_f32 %0, %1, %2" : "=v"(r) : "v"(a), "v"(b));
    return r;
}
static __device__ __forceinline__ bf16x8 ld_frag(const unsigned short* p) {
    uint4 u = *reinterpret_cast<const uint4*>(p);
    return __builtin_bit_cast(bf16x8, u);
}
// async global->LDS, 16B per lane. LDS dest must be wave-uniform-base + lane*16.
static __device__ __forceinline__ void cp16(unsigned short* lds, const unsigned short* g) {
    __builtin_amdgcn_global_load_lds(
        (const __attribute__((address_space(1))) unsigned int*)g,
        (__attribute__((address_space(3))) unsigned int*)lds, 16, 0, 0);
}
static __device__ __forceinline__ f32x4 mfma16(bf16x8 a, bf16x8 b, f32x4 c) {
    return __builtin_amdgcn_mfma_f32_16x16x32_bf16(a, b, c, 0, 0, 0);
}

// ---------------- pre-pass: fp32 -> bf16 convert ----------------
__global__ __launch_bounds__(256) void k_cvt(const float* __restrict__ in,
                                             unsigned short* __restrict__ out, int n) {
    int i = (blockIdx.x * 256 + threadIdx.x) * 4;
    if (i < n) {
        float4 v = *reinterpret_cast<const float4*>(in + i);
        uint2 o;
        o.x = pack2(v.x, v.y);
        o.y = pack2(v.z, v.w);
        *reinterpret_cast<uint2*>(out + i) = o;
    }
}

// ------------- pre-pass: transpose + convert weight: in fp32 [K][N] -> out bf16 [N][K]
__global__ __launch_bounds__(256) void k_wt(const float* __restrict__ in,
                                            unsigned short* __restrict__ out, int K, int N) {
    __shared__ float t[32][33];
    int n0 = blockIdx.x * 32, k0 = blockIdx.y * 32;
    int tx = threadIdx.x, ty = threadIdx.y; // blockDim (32,8)
    for (int j = 0; j < 4; j++) {
        int r = ty + j * 8;
        t[r][tx] = in[(size_t)(k0 + r) * N + n0 + tx];
    }
    __syncthreads();
    for (int j = 0; j < 4; j++) {
        int r = ty + j * 8;
        out[(size_t)(n0 + r) * K + k0 + tx] = f2bf(t[tx][r]);
    }
}

// ---------------- QKV GEMM (2-phase pipelined) + bias + split-heads epilogue ----------------
// 128x128 tile, dbuf LDS staging: issue stage(next K-step) BEFORE computing current, one
// vmcnt(0)+barrier per step (T3-min; same structure that won in k_attn). V-sector epilogue
// goes through an LDS transpose (pitch 132 shorts -> 8B-aligned rows, low-conflict) so V^T
// is written as coalesced 16B stores instead of 2B scatter at 4KB stride.
__global__ __launch_bounds__(256) void k_qkv(
    const unsigned short* __restrict__ Ab, const unsigned short* __restrict__ Wt,
    const float* __restrict__ bias,
    unsigned short* __restrict__ Qb, unsigned short* __restrict__ Kb,
    unsigned short* __restrict__ Vb)
{
    // 33792B shared: gemm uses [0,16384) shorts (As dbuf 2x4096, Bs dbuf 2x4096);
    // V-epilogue reuses all of it as vt[128 rows][132 pitch].
    __shared__ __attribute__((aligned(16))) unsigned short smem[16896];
    unsigned short* As = smem;          // [2][128*32]
    unsigned short* Bs = smem + 8192;   // [2][128*32]

    const int t = threadIdx.x;
    const int w = t >> 6, lane = t & 63, lr = lane & 15, lq = lane >> 4;
    const int wm = (w >> 1) * 64, wn = (w & 1) * 64;
    const int m0 = blockIdx.x * 128, n0 = blockIdx.y * 128;

    f32x4 acc[4][4];
    for (int mt = 0; mt < 4; mt++)
        for (int nt = 0; nt < 4; nt++)
            acc[mt][nt] = (f32x4){0.f, 0.f, 0.f, 0.f};

    auto stage = [&](int bb, int kt) {
        for (int i = 0; i < 2; i++) {
            int c = t + i * 256;          // 512 16B-chunks per operand
            int row = c >> 2, kp = (c & 3) * 8;
            cp16(&As[bb * 4096 + c * 8], &Ab[(size_t)(m0 + row) * E_ + kt + kp]);
        }
        for (int i = 0; i < 2; i++) {
            int c = t + i * 256;
            int row = c >> 2, kp = (c & 3) * 8;
            cp16(&Bs[bb * 4096 + c * 8], &Wt[(size_t)(n0 + row) * E_ + kt + kp]);
        }
    };

    stage(0, 0);
    asm volatile("s_waitcnt vmcnt(0)" ::: "memory");
    __syncthreads();

    int cur = 0;
    for (int kt = 0; kt < E_; kt += 32) {
        if (kt + 32 < E_) stage(cur ^ 1, kt + 32);
        const unsigned short* Ac = &As[cur * 4096];
        const unsigned short* Bc = &Bs[cur * 4096];
        bf16x8 af[4], bfr[4];
        for (int mt = 0; mt < 4; mt++) af[mt]  = ld_frag(&Ac[(wm + mt * 16 + lr) * 32 + lq * 8]);
        for (int nt = 0; nt < 4; nt++) bfr[nt] = ld_frag(&Bc[(wn + nt * 16 + lr) * 32 + lq * 8]);
        __builtin_amdgcn_s_setprio(1);
        for (int mt = 0; mt < 4; mt++)
            for (int nt = 0; nt < 4; nt++)
                acc[mt][nt] = mfma16(af[mt], bfr[nt], acc[mt][nt]);
        __builtin_amdgcn_s_setprio(0);
        asm volatile("s_waitcnt vmcnt(0)" ::: "memory");
        __syncthreads();
        cur ^= 1;
    }

    const int sector = (n0 >> 10);   // whole block maps to one of q/k/v (128 | 1024)
    if (sector != 2) {
        for (int nt = 0; nt < 4; nt++) {
            int n = n0 + wn + nt * 16 + lr;
            float bv = bias[n];
            int nn = n & 1023, h = nn >> 6, d = nn & 63;
            for (int mt = 0; mt < 4; mt++) {
                for (int i = 0; i < 4; i++) {
                    int tok = m0 + wm + mt * 16 + lq * 4 + i;
                    int b = tok >> 11, s = tok & 2047;
                    float v = acc[mt][nt][i] + bv;
                    if (sector == 0) {
                        // fold 1/sqrt(D)=0.125 AND log2(e) into Q: attn uses exp2 directly
                        Qb[(((size_t)(b * H_ + h) * S_ + s) << 6) + d] = f2bf(v * 0.18033688f);
                    } else {
                        Kb[(((size_t)(b * H_ + h) * S_ + s) << 6) + d] = f2bf(v);
                    }
                }
            }
        }
    } else {
        // V: transpose through LDS -> coalesced V^T [B,H,D,S] stores.
        // vt[row = hl*64+d][132 pitch], row covers this block's 2 heads x 64 d.
        // loop-end barrier already separates gemm's LDS use from this reuse.
        for (int nt = 0; nt < 4; nt++) {
            int nl = wn + nt * 16 + lr;           // 0..127
            int row = nl;                          // hl*64+d == nl
            float bv = bias[n0 + nl];
            unsigned short* vr = &smem[row * 132];
            for (int mt = 0; mt < 4; mt++) {
                int tokb = wm + mt * 16 + lq * 4;  // multiple of 4 -> 8B aligned
                uint2 pk;
                pk.x = cvt_pk(acc[mt][nt][0] + bv, acc[mt][nt][1] + bv);
                pk.y = cvt_pk(acc[mt][nt][2] + bv, acc[mt][nt][3] + bv);
                *reinterpret_cast<uint2*>(&vr[tokb]) = pk;
            }
        }
        __syncthreads();
        // read 128B row-segments, store coalesced: thread -> (row = t>>1, half = t&1)
        int row = t >> 1, half = t & 1;
        int hglob = ((n0 & 1023) >> 6) + (row >> 6), d = row & 63;
        int b = m0 >> 11, sbase = (m0 & 2047) + half * 64;
        size_t gb = (((size_t)(b * H_ + hglob) * D_ + d) << 11) + sbase;
        const unsigned short* src = &smem[row * 132 + half * 64];
        for (int jj = 0; jj < 8; jj++) {
            uint2 a = *reinterpret_cast<const uint2*>(&src[jj * 8]);
            uint2 bq = *reinterpret_cast<const uint2*>(&src[jj * 8 + 4]);
            uint4 o4; o4.x = a.x; o4.y = a.y; o4.z = bq.x; o4.w = bq.y;
            *reinterpret_cast<uint4*>(&Vb[gb + jj * 8]) = o4;
        }
    }
}

// ---------------- flash attention (no causal mask; no-max softmax, deferred l) ----------------
// 2-phase pipeline, 128-key macro-tiles (2x64 sub-tiles), dbuf K/V staging. Each wave owns
// 32 q-rows (two 16-row halves); K/V frags amortized over 2x MFMA. LDS = 80KB; grid 512 =
// 2 blocks/CU (grid-limited). All LDS surfaces dense with segment-XOR swizzle.
__global__ __launch_bounds__(256) void k_attn(
    const unsigned short* __restrict__ Qb, const unsigned short* __restrict__ Kb,
    const unsigned short* __restrict__ Vb, unsigned short* __restrict__ Ob)
{
    __shared__ __attribute__((aligned(16))) unsigned short Ks[2][128 * 64];  // [buf][key][d]
    __shared__ __attribute__((aligned(16))) unsigned short Vt[2][64 * 128];  // [buf][d][key]
    __shared__ __attribute__((aligned(16))) unsigned short Ps[4][32 * 64];   // per-wave P[q32][key64]

    const int t = threadIdx.x, w = t >> 6, lane = t & 63, lr = lane & 15, lq = lane >> 4;
    const int h = blockIdx.y, b = blockIdx.z;
    const size_t head = ((size_t)(b * H_ + h)) * (S_ * D_);
    const unsigned short* Qh = Qb + head;
    const unsigned short* Kh = Kb + head;
    const unsigned short* Vh = Vb + head;   // [D][S]
    const int q0 = blockIdx.x * 128 + w * 16;   // wave's q-halves: q0, q0+64
    const int swz = lr & 7;

    // Q fragments (B-operand): lane holds Q[q][d = kk*32 + lq*8 ..+8]; scale pre-folded
    bf16x8 qa[2][2];
    for (int qh = 0; qh < 2; qh++)
        for (int kk = 0; kk < 2; kk++)
            qa[qh][kk] = ld_frag(&Qh[(size_t)(q0 + qh * 64 + lr) * 64 + kk * 32 + lq * 8]);

    f32x4 o[2][4];
    for (int qh = 0; qh < 2; qh++)
        for (int i = 0; i < 4; i++) o[qh][i] = (f32x4){0.f, 0.f, 0.f, 0.f};
    float lsum[2] = {0.f, 0.f};
    unsigned short* Pw = Ps[w];

    // stage one 128-key tile into buffer bb:
    // K 128 rows x 8 segs of 16B (seg ^ row&7); V^T 64 rows x 16 segs (low-3-bit XOR by d)
    auto stage = [&](int bb, int kt) {
        for (int i = 0; i < 4; i++) {
            int c = t + i * 256;                          // 1024 chunks of 16B
            int row = c >> 3, sp = c & 7;
            cp16(&Ks[bb][c * 8], &Kh[(size_t)(kt + row) * 64 + (sp ^ (row & 7)) * 8]);
        }
        for (int i = 0; i < 4; i++) {
            int c = t + i * 256;
            int d = c >> 4, sp = c & 15, seg = (sp & 8) | ((sp & 7) ^ (d & 7));
            cp16(&Vt[bb][c * 8], &Vh[(size_t)d * S_ + kt + seg * 8]);
        }
    };

    stage(0, 0);
    asm volatile("s_waitcnt vmcnt(0)" ::: "memory");
    __syncthreads();

    int cur = 0;
#pragma unroll 2
    for (int kt = 0; kt < S_; kt += 128) {
        // issue next tile's loads first -- latency hides under this tile's compute
        if (kt + 128 < S_) stage(cur ^ 1, kt + 128);

        const unsigned short* Kc = Ks[cur];
        const unsigned short* Vc = Vt[cur];

#pragma unroll
        for (int ss = 0; ss < 2; ss++) {
            // scores: S^T[key][q], 4 key-tiles of 16 per sub-tile; K-frags reused across both
            // q-halves. lane reg r holds key = ss*64 + tau*16 + lq*4 + r, q = (qh*64)+lr
            for (int tau = 0; tau < 4; tau++) {
                int krow = ss * 64 + tau * 16 + lr;
                bf16x8 kf0 = ld_frag(&Kc[krow * 64 + ((0 + lq) ^ swz) * 8]);
                bf16x8 kf1 = ld_frag(&Kc[krow * 64 + ((4 + lq) ^ swz) * 8]);
                for (int qh = 0; qh < 2; qh++) {
                    f32x4 z = (f32x4){0.f, 0.f, 0.f, 0.f};
                    __builtin_amdgcn_s_setprio(1);
                    z = mfma16(kf0, qa[qh][0], z);
                    z = mfma16(kf1, qa[qh][1], z);
                    __builtin_amdgcn_s_setprio(0);
                    float e0 = __builtin_amdgcn_exp2f(z[0]);  // log2e folded into Q scale
                    float e1 = __builtin_amdgcn_exp2f(z[1]);
                    float e2 = __builtin_amdgcn_exp2f(z[2]);
                    float e3 = __builtin_amdgcn_exp2f(z[3]);
                    lsum[qh] += (e0 + e1) + (e2 + e3);
                    // P[q][key-within-subtile]: 4 consecutive keys -> one b64 write
                    uint2 pk;
                    pk.x = cvt_pk(e0, e1);
                    pk.y = cvt_pk(e2, e3);
                    int seg = (tau * 2 + (lq >> 1)) ^ swz;
                    *reinterpret_cast<uint2*>(&Pw[(qh * 16 + lr) * 64 + seg * 8 + (lq & 1) * 4]) = pk;
                }
            }
            // PV: O^T[d][q] += V^T * P^T ; A = Vt rows, B = P rows (wave-private, in-order DS).
            // V-frags reused across both q-halves.
            for (int kk = 0; kk < 2; kk++) {
                bf16x8 pf0 = ld_frag(&Pw[(lr) * 64 + ((kk * 4 + lq) ^ swz) * 8]);
                bf16x8 pf1 = ld_frag(&Pw[(16 + lr) * 64 + ((kk * 4 + lq) ^ swz) * 8]);
                __builtin_amdgcn_s_setprio(1);
                for (int t2 = 0; t2 < 4; t2++) {
                    int vrow = t2 * 16 + lr;
                    bf16x8 vf = ld_frag(&Vc[vrow * 128 + ((ss * 8) | ((kk * 4 + lq) ^ swz)) * 8]);
                    o[0][t2] = mfma16(vf, pf0, o[0][t2]);
                    o[1][t2] = mfma16(vf, pf1, o[1][t2]);
                }
                __builtin_amdgcn_s_setprio(0);
            }
        }

        // drain next-tile stage (hidden under compute) + single barrier per 128-key tile
        asm volatile("s_waitcnt vmcnt(0)" ::: "memory");
        __syncthreads();
        cur ^= 1;
    }

    // deferred softmax denominator: reduce across the 4 lq groups; then epilogue per q-half.
    for (int qh = 0; qh < 2; qh++) {
        float ls = lsum[qh];
        ls += __shfl_xor(ls, 16, 64);
        ls += __shfl_xor(ls, 32, 64);
        float inv = 1.0f / ls;

        // lane holds O^T[d = t2*16+lq*4+r][q = lr] -> Ob[(b,s)][h*64+d], b64 stores
        int s = q0 + qh * 64 + lr;
        size_t rowoff = ((size_t)(b * S_ + s)) * E_ + h * 64;
        for (int t2 = 0; t2 < 4; t2++) {
            uint2 pk;
            pk.x = cvt_pk(o[qh][t2][0] * inv, o[qh][t2][1] * inv);
            pk.y = cvt_pk(o[qh][t2][2] * inv, o[qh][t2][3] * inv);
            *reinterpret_cast<uint2*>(&Ob[rowoff + t2 * 16 + lq * 4]) = pk;
        }
    }
}

// ---------------- output projection (2-phase pipelined) + bias -> fp32 out ----------------
// 128x64 tile (512 blocks = 2/CU), dbuf staging with issue-early stage + single barrier/step.
__global__ __launch_bounds__(256) void k_proj(
    const unsigned short* __restrict__ Ab, const unsigned short* __restrict__ Wt,
    const float* __restrict__ bias, float* __restrict__ out)
{
    __shared__ __attribute__((aligned(16))) unsigned short smem[12288]; // As dbuf 8192 + Bs dbuf 4096
    unsigned short* As = smem;           // [2][128*32]
    unsigned short* Bs = smem + 8192;    // [2][64*32]

    const int t = threadIdx.x;
    const int w = t >> 6, lane = t & 63, lr = lane & 15, lq = lane >> 4;
    const int wm = (w >> 1) * 64, wn = (w & 1) * 32;
    const int m0 = blockIdx.x * 128, n0 = blockIdx.y * 64;

    f32x4 acc[4][2];
    for (int mt = 0; mt < 4; mt++)
        for (int nt = 0; nt < 2; nt++)
            acc[mt][nt] = (f32x4){0.f, 0.f, 0.f, 0.f};

    auto stage = [&](int bb, int kt) {
        for (int i = 0; i < 2; i++) {
            int c = t + i * 256;          // A: 512 16B-chunks
            int row = c >> 2, kp = (c & 3) * 8;
            cp16(&As[bb * 4096 + c * 8], &Ab[(size_t)(m0 + row) * E_ + kt + kp]);
        }
        {
            int c = t;                    // B: 256 16B-chunks
            int row = c >> 2, kp = (c & 3) * 8;
            cp16(&Bs[bb * 2048 + c * 8], &Wt[(size_t)(n0 + row) * E_ + kt + kp]);
        }
    };

    stage(0, 0);
    asm volatile("s_waitcnt vmcnt(0)" ::: "memory");
    __syncthreads();

    int cur = 0;
    for (int kt = 0; kt < E_; kt += 32) {
        if (kt + 32 < E_) stage(cur ^ 1, kt + 32);
        const unsigned short* Ac = &As[cur * 4096];
        const unsigned short* Bc = &Bs[cur * 2048];
        bf16x8 af[4], bfr[2];
        for (int mt = 0; mt < 4; mt++) af[mt]  = ld_frag(&Ac[(wm + mt * 16 + lr) * 32 + lq * 8]);
        for (int nt = 0; nt < 2; nt++) bfr[nt] = ld_frag(&Bc[(wn + nt * 16 + lr) * 32 + lq * 8]);
        __builtin_amdgcn_s_setprio(1);
        for (int mt = 0; mt < 4; mt++)
            for (int nt = 0; nt < 2; nt++)
                acc[mt][nt] = mfma16(af[mt], bfr[nt], acc[mt][nt]);
        __builtin_amdgcn_s_setprio(0);
        asm volatile("s_waitcnt vmcnt(0)" ::: "memory");
        __syncthreads();
        cur ^= 1;
    }

    for (int nt = 0; nt < 2; nt++) {
        int n = n0 + wn + nt * 16 + lr;
        float bv = bias[n];
        for (int mt = 0; mt < 4; mt++)
            for (int i = 0; i < 4; i++) {
                int tok = m0 + wm + mt * 16 + lq * 4 + i;
                out[(size_t)tok * E_ + n] = acc[mt][nt][i] + bv;
            }
    }
}

extern "C" void kernel_launch(void* const* d_in, const int* in_sizes, int n_in,
                              void* d_out, int out_size, void* d_ws, size_t ws_size,
                              hipStream_t stream) {
    const float* hs = (const float*)d_in[0];   // [2,2048,1024]
    const float* w1 = (const float*)d_in[1];   // [1024,3072]
    const float* b1 = (const float*)d_in[2];   // [3072]
    const float* w2 = (const float*)d_in[3];   // [1024,1024]
    const float* b2 = (const float*)d_in[4];   // [1024]
    float* out = (float*)d_out;

    char* ws = (char*)d_ws;
    unsigned short* hb  = (unsigned short*)(ws);                       // 8 MB hidden bf16
    unsigned short* w1t = (unsigned short*)(ws + (size_t)( 8 << 20));  // 6 MB W_qkv^T bf16
    unsigned short* w2t = (unsigned short*)(ws + (size_t)(14 << 20));  // 2 MB W_proj^T bf16
    unsigned short* Qb  = (unsigned short*)(ws + (size_t)(16 << 20));  // 8 MB [B,H,S,D] (pre-scaled)
    unsigned short* Kb  = (unsigned short*)(ws + (size_t)(24 << 20));  // 8 MB [B,H,S,D]
    unsigned short* Vb  = (unsigned short*)(ws + (size_t)(32 << 20));  // 8 MB [B,H,D,S]
    unsigned short* Ao  = (unsigned short*)(ws + (size_t)(40 << 20));  // 8 MB [T,E]

    k_cvt<<<dim3(T_ * E_ / 1024), dim3(256), 0, stream>>>(hs, hb, T_ * E_);
    k_wt<<<dim3(NQ_ / 32, E_ / 32), dim3(32, 8), 0, stream>>>(w1, w1t, E_, NQ_);
    k_wt<<<dim3(E_ / 32, E_ / 32), dim3(32, 8), 0, stream>>>(w2, w2t, E_, E_);
    k_qkv<<<dim3(T_ / 128, NQ_ / 128), dim3(256), 0, stream>>>(hb, w1t, b1, Qb, Kb, Vb);
    k_attn<<<dim3(S_ / 128, H_, B_), dim3(256), 0, stream>>>(Qb, Kb, Vb, Ao);
    k_proj<<<dim3(T_ / 128, E_ / 64), dim3(256), 0, stream>>>(Ao, w2t, b2, out);
}

// Round 5
// 200.025 us; speedup vs baseline: 1.0121x; 1.0121x over previous
//
#include <hip/hip_runtime.h>
#include <hip/hip_bf16.h>
#include <cstdint>
#include <cstddef>

#define E_ 1024
#define H_ 16
#define D_ 64
#define B_ 2
#define S_ 2048
#define T_ 4096   // B_*S_
#define NQ_ 3072  // 3*E_

typedef __bf16 bf16_t;
typedef bf16_t bf16x8 __attribute__((ext_vector_type(8)));
typedef float f32x4 __attribute__((ext_vector_type(4)));

static __device__ __forceinline__ unsigned short f2bf(float f) {
    __hip_bfloat16 h = __float2bfloat16(f);
    return __builtin_bit_cast(unsigned short, h);
}
static __device__ __forceinline__ unsigned pack2(float a, float b) {
    return (unsigned)f2bf(a) | ((unsigned)f2bf(b) << 16);
}
// HW packed f32->bf16 (RNE), 1 instruction. T12 recipe (no builtin on gfx950).
static __device__ __forceinline__ unsigned cvt_pk(float a, float b) {
    unsigned r;
    asm("v_cvt_pk_bf16_f32 %0, %1, %2" : "=v"(r) : "v"(a), "v"(b));
    return r;
}
static __device__ __forceinline__ bf16x8 ld_frag(const unsigned short* p) {
    uint4 u = *reinterpret_cast<const uint4*>(p);
    return __builtin_bit_cast(bf16x8, u);
}
// async global->LDS, 16B per lane. LDS dest must be wave-uniform-base + lane*16.
static __device__ __forceinline__ void cp16(unsigned short* lds, const unsigned short* g) {
    __builtin_amdgcn_global_load_lds(
        (const __attribute__((address_space(1))) unsigned int*)g,
        (__attribute__((address_space(3))) unsigned int*)lds, 16, 0, 0);
}
static __device__ __forceinline__ f32x4 mfma16(bf16x8 a, bf16x8 b, f32x4 c) {
    return __builtin_amdgcn_mfma_f32_16x16x32_bf16(a, b, c, 0, 0, 0);
}

// ---------------- pre-pass: fp32 -> bf16 convert ----------------
__global__ __launch_bounds__(256) void k_cvt(const float* __restrict__ in,
                                             unsigned short* __restrict__ out, int n) {
    int i = (blockIdx.x * 256 + threadIdx.x) * 4;
    if (i < n) {
        float4 v = *reinterpret_cast<const float4*>(in + i);
        uint2 o;
        o.x = pack2(v.x, v.y);
        o.y = pack2(v.z, v.w);
        *reinterpret_cast<uint2*>(out + i) = o;
    }
}

// ------------- pre-pass: transpose + convert weight: in fp32 [K][N] -> out bf16 [N][K]
__global__ __launch_bounds__(256) void k_wt(const float* __restrict__ in,
                                            unsigned short* __restrict__ out, int K, int N) {
    __shared__ float t[32][33];
    int n0 = blockIdx.x * 32, k0 = blockIdx.y * 32;
    int tx = threadIdx.x, ty = threadIdx.y; // blockDim (32,8)
    for (int j = 0; j < 4; j++) {
        int r = ty + j * 8;
        t[r][tx] = in[(size_t)(k0 + r) * N + n0 + tx];
    }
    __syncthreads();
    for (int j = 0; j < 4; j++) {
        int r = ty + j * 8;
        out[(size_t)(n0 + r) * K + k0 + tx] = f2bf(t[tx][r]);
    }
}

// ---------------- QKV GEMM + bias + split-heads epilogue ----------------
// m97-style 2-barrier schedule at BK=64: 16 K-steps (half the barriers of BK=32), 32 MFMA
// per step. Staging uses the attn-proven XOR-swizzle (chunk sp holds global seg sp^(row&7))
// so fragment reads hit sp=(kk*4+lq)^(lr&7): 2 lanes/bank -> conflict-free (m136), vs the
// 8-way conflict of the unswizzled BK=32 layout (m98: 1.7e7 conflicts). No setprio (m190:
// hurts lockstep GEMM), no manual pipeline (R4 regression).
__global__ __launch_bounds__(256) void k_qkv(
    const unsigned short* __restrict__ Ab, const unsigned short* __restrict__ Wt,
    const float* __restrict__ bias,
    unsigned short* __restrict__ Qb, unsigned short* __restrict__ Kb,
    unsigned short* __restrict__ Vb)
{
    __shared__ __attribute__((aligned(16))) unsigned short As[128 * 64];
    __shared__ __attribute__((aligned(16))) unsigned short Bs[128 * 64];

    const int t = threadIdx.x;
    const int w = t >> 6, lane = t & 63, lr = lane & 15, lq = lane >> 4;
    const int wm = (w >> 1) * 64, wn = (w & 1) * 64;
    const int m0 = blockIdx.x * 128, n0 = blockIdx.y * 128;
    const int swz = lr & 7;

    f32x4 acc[4][4];
    for (int mt = 0; mt < 4; mt++)
        for (int nt = 0; nt < 4; nt++)
            acc[mt][nt] = (f32x4){0.f, 0.f, 0.f, 0.f};

    for (int kt = 0; kt < E_; kt += 64) {
        __syncthreads();
        for (int i = 0; i < 4; i++) {
            int c = t + i * 256;              // 1024 16B-chunks (128 rows x 8 segs)
            int row = c >> 3, sp = c & 7;
            cp16(&As[c * 8], &Ab[(size_t)(m0 + row) * E_ + kt + ((sp ^ (row & 7)) * 8)]);
        }
        for (int i = 0; i < 4; i++) {
            int c = t + i * 256;
            int row = c >> 3, sp = c & 7;
            cp16(&Bs[c * 8], &Wt[(size_t)(n0 + row) * E_ + kt + ((sp ^ (row & 7)) * 8)]);
        }
        __syncthreads();
        bf16x8 bfr[4][2];
        for (int nt = 0; nt < 4; nt++)
            for (int kk = 0; kk < 2; kk++)
                bfr[nt][kk] = ld_frag(&Bs[(wn + nt * 16 + lr) * 64 + (((kk * 4 + lq) ^ swz) * 8)]);
        for (int mt = 0; mt < 4; mt++) {
            bf16x8 af0 = ld_frag(&As[(wm + mt * 16 + lr) * 64 + (((0 + lq) ^ swz) * 8)]);
            bf16x8 af1 = ld_frag(&As[(wm + mt * 16 + lr) * 64 + (((4 + lq) ^ swz) * 8)]);
            for (int nt = 0; nt < 4; nt++) {
                acc[mt][nt] = mfma16(af0, bfr[nt][0], acc[mt][nt]);
                acc[mt][nt] = mfma16(af1, bfr[nt][1], acc[mt][nt]);
            }
        }
    }

    const int sector = (n0 >> 10);   // whole block maps to one of q/k/v (128 | 1024)
    for (int nt = 0; nt < 4; nt++) {
        int n = n0 + wn + nt * 16 + lr;
        float bv = bias[n];
        int nn = n & 1023, h = nn >> 6, d = nn & 63;
        for (int mt = 0; mt < 4; mt++) {
            for (int i = 0; i < 4; i++) {
                int tok = m0 + wm + mt * 16 + lq * 4 + i;
                int b = tok >> 11, s = tok & 2047;
                float v = acc[mt][nt][i] + bv;
                if (sector == 0) {
                    // fold 1/sqrt(D)=0.125 AND log2(e) into Q: attn uses exp2 directly
                    Qb[(((size_t)(b * H_ + h) * S_ + s) << 6) + d] = f2bf(v * 0.18033688f);
                } else if (sector == 1) {
                    Kb[(((size_t)(b * H_ + h) * S_ + s) << 6) + d] = f2bf(v);
                } else {
                    Vb[(((size_t)(b * H_ + h) * D_ + d) << 11) + s] = f2bf(v);  // V^T [B,H,D,S]
                }
            }
        }
    }
}

// ---------------- flash attention (no causal mask; no-max softmax, deferred l) ----------------
// 2-phase pipeline, 128-key macro-tiles (2x64 sub-tiles), dbuf K/V staging. Each wave owns
// 32 q-rows (two 16-row halves); K/V frags amortized over 2x MFMA. LDS = 80KB; grid 512 =
// 2 blocks/CU (grid-limited). All LDS surfaces dense with segment-XOR swizzle.
__global__ __launch_bounds__(256) void k_attn(
    const unsigned short* __restrict__ Qb, const unsigned short* __restrict__ Kb,
    const unsigned short* __restrict__ Vb, unsigned short* __restrict__ Ob)
{
    __shared__ __attribute__((aligned(16))) unsigned short Ks[2][128 * 64];  // [buf][key][d]
    __shared__ __attribute__((aligned(16))) unsigned short Vt[2][64 * 128];  // [buf][d][key]
    __shared__ __attribute__((aligned(16))) unsigned short Ps[4][32 * 64];   // per-wave P[q32][key64]

    const int t = threadIdx.x, w = t >> 6, lane = t & 63, lr = lane & 15, lq = lane >> 4;
    const int h = blockIdx.y, b = blockIdx.z;
    const size_t head = ((size_t)(b * H_ + h)) * (S_ * D_);
    const unsigned short* Qh = Qb + head;
    const unsigned short* Kh = Kb + head;
    const unsigned short* Vh = Vb + head;   // [D][S]
    const int q0 = blockIdx.x * 128 + w * 16;   // wave's q-halves: q0, q0+64
    const int swz = lr & 7;

    // Q fragments (B-operand): lane holds Q[q][d = kk*32 + lq*8 ..+8]; scale pre-folded
    bf16x8 qa[2][2];
    for (int qh = 0; qh < 2; qh++)
        for (int kk = 0; kk < 2; kk++)
            qa[qh][kk] = ld_frag(&Qh[(size_t)(q0 + qh * 64 + lr) * 64 + kk * 32 + lq * 8]);

    f32x4 o[2][4];
    for (int qh = 0; qh < 2; qh++)
        for (int i = 0; i < 4; i++) o[qh][i] = (f32x4){0.f, 0.f, 0.f, 0.f};
    float lsum[2] = {0.f, 0.f};
    unsigned short* Pw = Ps[w];

    // stage one 128-key tile into buffer bb:
    // K 128 rows x 8 segs of 16B (seg ^ row&7); V^T 64 rows x 16 segs (low-3-bit XOR by d)
    auto stage = [&](int bb, int kt) {
        for (int i = 0; i < 4; i++) {
            int c = t + i * 256;                          // 1024 chunks of 16B
            int row = c >> 3, sp = c & 7;
            cp16(&Ks[bb][c * 8], &Kh[(size_t)(kt + row) * 64 + (sp ^ (row & 7)) * 8]);
        }
        for (int i = 0; i < 4; i++) {
            int c = t + i * 256;
            int d = c >> 4, sp = c & 15, seg = (sp & 8) | ((sp & 7) ^ (d & 7));
            cp16(&Vt[bb][c * 8], &Vh[(size_t)d * S_ + kt + seg * 8]);
        }
    };

    stage(0, 0);
    asm volatile("s_waitcnt vmcnt(0)" ::: "memory");
    __syncthreads();

    int cur = 0;
#pragma unroll 2
    for (int kt = 0; kt < S_; kt += 128) {
        // issue next tile's loads first -- latency hides under this tile's compute
        if (kt + 128 < S_) stage(cur ^ 1, kt + 128);

        const unsigned short* Kc = Ks[cur];
        const unsigned short* Vc = Vt[cur];

#pragma unroll
        for (int ss = 0; ss < 2; ss++) {
            // scores: S^T[key][q], 4 key-tiles of 16 per sub-tile; K-frags reused across both
            // q-halves. lane reg r holds key = ss*64 + tau*16 + lq*4 + r, q = (qh*64)+lr
            for (int tau = 0; tau < 4; tau++) {
                int krow = ss * 64 + tau * 16 + lr;
                bf16x8 kf0 = ld_frag(&Kc[krow * 64 + ((0 + lq) ^ swz) * 8]);
                bf16x8 kf1 = ld_frag(&Kc[krow * 64 + ((4 + lq) ^ swz) * 8]);
                for (int qh = 0; qh < 2; qh++) {
                    f32x4 z = (f32x4){0.f, 0.f, 0.f, 0.f};
                    __builtin_amdgcn_s_setprio(1);
                    z = mfma16(kf0, qa[qh][0], z);
                    z = mfma16(kf1, qa[qh][1], z);
                    __builtin_amdgcn_s_setprio(0);
                    float e0 = __builtin_amdgcn_exp2f(z[0]);  // log2e folded into Q scale
                    float e1 = __builtin_amdgcn_exp2f(z[1]);
                    float e2 = __builtin_amdgcn_exp2f(z[2]);
                    float e3 = __builtin_amdgcn_exp2f(z[3]);
                    lsum[qh] += (e0 + e1) + (e2 + e3);
                    // P[q][key-within-subtile]: 4 consecutive keys -> one b64 write
                    uint2 pk;
                    pk.x = cvt_pk(e0, e1);
                    pk.y = cvt_pk(e2, e3);
                    int seg = (tau * 2 + (lq >> 1)) ^ swz;
                    *reinterpret_cast<uint2*>(&Pw[(qh * 16 + lr) * 64 + seg * 8 + (lq & 1) * 4]) = pk;
                }
            }
            // PV: O^T[d][q] += V^T * P^T ; A = Vt rows, B = P rows (wave-private, in-order DS).
            // V-frags reused across both q-halves.
            for (int kk = 0; kk < 2; kk++) {
                bf16x8 pf0 = ld_frag(&Pw[(lr) * 64 + ((kk * 4 + lq) ^ swz) * 8]);
                bf16x8 pf1 = ld_frag(&Pw[(16 + lr) * 64 + ((kk * 4 + lq) ^ swz) * 8]);
                __builtin_amdgcn_s_setprio(1);
                for (int t2 = 0; t2 < 4; t2++) {
                    int vrow = t2 * 16 + lr;
                    bf16x8 vf = ld_frag(&Vc[vrow * 128 + ((ss * 8) | ((kk * 4 + lq) ^ swz)) * 8]);
                    o[0][t2] = mfma16(vf, pf0, o[0][t2]);
                    o[1][t2] = mfma16(vf, pf1, o[1][t2]);
                }
                __builtin_amdgcn_s_setprio(0);
            }
        }

        // drain next-tile stage (hidden under compute) + single barrier per 128-key tile
        asm volatile("s_waitcnt vmcnt(0)" ::: "memory");
        __syncthreads();
        cur ^= 1;
    }

    // deferred softmax denominator: reduce across the 4 lq groups; then epilogue per q-half.
    for (int qh = 0; qh < 2; qh++) {
        float ls = lsum[qh];
        ls += __shfl_xor(ls, 16, 64);
        ls += __shfl_xor(ls, 32, 64);
        float inv = 1.0f / ls;

        // lane holds O^T[d = t2*16+lq*4+r][q = lr] -> Ob[(b,s)][h*64+d], b64 stores
        int s = q0 + qh * 64 + lr;
        size_t rowoff = ((size_t)(b * S_ + s)) * E_ + h * 64;
        for (int t2 = 0; t2 < 4; t2++) {
            uint2 pk;
            pk.x = cvt_pk(o[qh][t2][0] * inv, o[qh][t2][1] * inv);
            pk.y = cvt_pk(o[qh][t2][2] * inv, o[qh][t2][3] * inv);
            *reinterpret_cast<uint2*>(&Ob[rowoff + t2 * 16 + lq * 4]) = pk;
        }
    }
}

// ---------------- output projection + bias -> fp32 out ----------------
// 128x64 tile (512 blocks = 2/CU), BK=64 with XOR-swizzled staging (same as k_qkv),
// 2-barrier m97-style schedule.
__global__ __launch_bounds__(256) void k_proj(
    const unsigned short* __restrict__ Ab, const unsigned short* __restrict__ Wt,
    const float* __restrict__ bias, float* __restrict__ out)
{
    __shared__ __attribute__((aligned(16))) unsigned short As[128 * 64];
    __shared__ __attribute__((aligned(16))) unsigned short Bs[64 * 64];

    const int t = threadIdx.x;
    const int w = t >> 6, lane = t & 63, lr = lane & 15, lq = lane >> 4;
    const int wm = (w >> 1) * 64, wn = (w & 1) * 32;
    const int m0 = blockIdx.x * 128, n0 = blockIdx.y * 64;
    const int swz = lr & 7;

    f32x4 acc[4][2];
    for (int mt = 0; mt < 4; mt++)
        for (int nt = 0; nt < 2; nt++)
            acc[mt][nt] = (f32x4){0.f, 0.f, 0.f, 0.f};

    for (int kt = 0; kt < E_; kt += 64) {
        __syncthreads();
        for (int i = 0; i < 4; i++) {
            int c = t + i * 256;              // A: 1024 chunks (128 rows x 8 segs)
            int row = c >> 3, sp = c & 7;
            cp16(&As[c * 8], &Ab[(size_t)(m0 + row) * E_ + kt + ((sp ^ (row & 7)) * 8)]);
        }
        for (int i = 0; i < 2; i++) {
            int c = t + i * 256;              // B: 512 chunks (64 rows x 8 segs)
            int row = c >> 3, sp = c & 7;
            cp16(&Bs[c * 8], &Wt[(size_t)(n0 + row) * E_ + kt + ((sp ^ (row & 7)) * 8)]);
        }
        __syncthreads();
        bf16x8 bfr[2][2];
        for (int nt = 0; nt < 2; nt++)
            for (int kk = 0; kk < 2; kk++)
                bfr[nt][kk] = ld_frag(&Bs[(wn + nt * 16 + lr) * 64 + (((kk * 4 + lq) ^ swz) * 8)]);
        for (int mt = 0; mt < 4; mt++) {
            bf16x8 af0 = ld_frag(&As[(wm + mt * 16 + lr) * 64 + (((0 + lq) ^ swz) * 8)]);
            bf16x8 af1 = ld_frag(&As[(wm + mt * 16 + lr) * 64 + (((4 + lq) ^ swz) * 8)]);
            for (int nt = 0; nt < 2; nt++) {
                acc[mt][nt] = mfma16(af0, bfr[nt][0], acc[mt][nt]);
                acc[mt][nt] = mfma16(af1, bfr[nt][1], acc[mt][nt]);
            }
        }
    }

    for (int nt = 0; nt < 2; nt++) {
        int n = n0 + wn + nt * 16 + lr;
        float bv = bias[n];
        for (int mt = 0; mt < 4; mt++)
            for (int i = 0; i < 4; i++) {
                int tok = m0 + wm + mt * 16 + lq * 4 + i;
                out[(size_t)tok * E_ + n] = acc[mt][nt][i] + bv;
            }
    }
}

extern "C" void kernel_launch(void* const* d_in, const int* in_sizes, int n_in,
                              void* d_out, int out_size, void* d_ws, size_t ws_size,
                              hipStream_t stream) {
    const float* hs = (const float*)d_in[0];   // [2,2048,1024]
    const float* w1 = (const float*)d_in[1];   // [1024,3072]
    const float* b1 = (const float*)d_in[2];   // [3072]
    const float* w2 = (const float*)d_in[3];   // [1024,1024]
    const float* b2 = (const float*)d_in[4];   // [1024]
    float* out = (float*)d_out;

    char* ws = (char*)d_ws;
    unsigned short* hb  = (unsigned short*)(ws);                       // 8 MB hidden bf16
    unsigned short* w1t = (unsigned short*)(ws + (size_t)( 8 << 20));  // 6 MB W_qkv^T bf16
    unsigned short* w2t = (unsigned short*)(ws + (size_t)(14 << 20));  // 2 MB W_proj^T bf16
    unsigned short* Qb  = (unsigned short*)(ws + (size_t)(16 << 20));  // 8 MB [B,H,S,D] (pre-scaled)
    unsigned short* Kb  = (unsigned short*)(ws + (size_t)(24 << 20));  // 8 MB [B,H,S,D]
    unsigned short* Vb  = (unsigned short*)(ws + (size_t)(32 << 20));  // 8 MB [B,H,D,S]
    unsigned short* Ao  = (unsigned short*)(ws + (size_t)(40 << 20));  // 8 MB [T,E]

    k_cvt<<<dim3(T_ * E_ / 1024), dim3(256), 0, stream>>>(hs, hb, T_ * E_);
    k_wt<<<dim3(NQ_ / 32, E_ / 32), dim3(32, 8), 0, stream>>>(w1, w1t, E_, NQ_);
    k_wt<<<dim3(E_ / 32, E_ / 32), dim3(32, 8), 0, stream>>>(w2, w2t, E_, E_);
    k_qkv<<<dim3(T_ / 128, NQ_ / 128), dim3(256), 0, stream>>>(hb, w1t, b1, Qb, Kb, Vb);
    k_attn<<<dim3(S_ / 128, H_, B_), dim3(256), 0, stream>>>(Qb, Kb, Vb, Ao);
    k_proj<<<dim3(T_ / 128, E_ / 64), dim3(256), 0, stream>>>(Ao, w2t, b2, out);
}

// Round 6
// 190.317 us; speedup vs baseline: 1.0638x; 1.0510x over previous
//
#include <hip/hip_runtime.h>
#include <hip/hip_bf16.h>
#include <cstdint>
#include <cstddef>

#define E_ 1024
#define H_ 16
#define D_ 64
#define B_ 2
#define S_ 2048
#define T_ 4096   // B_*S_
#define NQ_ 3072  // 3*E_

typedef __bf16 bf16_t;
typedef bf16_t bf16x8 __attribute__((ext_vector_type(8)));
typedef float f32x4 __attribute__((ext_vector_type(4)));

static __device__ __forceinline__ unsigned short f2bf(float f) {
    __hip_bfloat16 h = __float2bfloat16(f);
    return __builtin_bit_cast(unsigned short, h);
}
// HW packed f32->bf16 (RNE), 1 instruction. T12 recipe (no builtin on gfx950).
static __device__ __forceinline__ unsigned cvt_pk(float a, float b) {
    unsigned r;
    asm("v_cvt_pk_bf16_f32 %0, %1, %2" : "=v"(r) : "v"(a), "v"(b));
    return r;
}
static __device__ __forceinline__ bf16x8 ld_frag(const unsigned short* p) {
    uint4 u = *reinterpret_cast<const uint4*>(p);
    return __builtin_bit_cast(bf16x8, u);
}
// async global->LDS, 16B per lane. LDS dest must be wave-uniform-base + lane*16.
static __device__ __forceinline__ void cp16(unsigned short* lds, const unsigned short* g) {
    __builtin_amdgcn_global_load_lds(
        (const __attribute__((address_space(1))) unsigned int*)g,
        (__attribute__((address_space(3))) unsigned int*)lds, 16, 0, 0);
}
static __device__ __forceinline__ f32x4 mfma16(bf16x8 a, bf16x8 b, f32x4 c) {
    return __builtin_amdgcn_mfma_f32_16x16x32_bf16(a, b, c, 0, 0, 0);
}

// ------------- pre-pass (fused): transpose+convert BOTH weights: fp32 [K][N] -> bf16 [N][K]
// blockIdx.x < 96 -> w1 (N=3072); else -> w2 (N=1024). One launch instead of two.
__global__ __launch_bounds__(256) void k_wt2(
    const float* __restrict__ w1, unsigned short* __restrict__ w1t,
    const float* __restrict__ w2, unsigned short* __restrict__ w2t)
{
    __shared__ float tbuf[32][33];
    const float* in;
    unsigned short* out;
    int N, bx;
    if (blockIdx.x < 96) { in = w1; out = w1t; N = NQ_; bx = blockIdx.x; }
    else                 { in = w2; out = w2t; N = E_;  bx = blockIdx.x - 96; }
    int n0 = bx * 32, k0 = blockIdx.y * 32;
    int tx = threadIdx.x, ty = threadIdx.y; // blockDim (32,8)
    for (int j = 0; j < 4; j++) {
        int r = ty + j * 8;
        tbuf[r][tx] = in[(size_t)(k0 + r) * N + n0 + tx];
    }
    __syncthreads();
    for (int j = 0; j < 4; j++) {
        int r = ty + j * 8;
        out[(size_t)(n0 + r) * E_ + k0 + tx] = f2bf(tbuf[tx][r]);
    }
}

// ---------------- QKV GEMM + bias + split-heads epilogue ----------------
// R3-exact m97 schedule (BK=32, 2 barriers/step, no pipeline/setprio — R4/R5 both regressed).
// A is staged DIRECTLY from fp32 hidden_states: float4 load -> cvt_pk -> ds_write_b64
// (conflict-free banks), eliminating the k_cvt pre-pass and its 16MB round-trip. B still
// streams async via global_load_lds and overlaps A's load+convert.
__global__ __launch_bounds__(256) void k_qkv(
    const float* __restrict__ Hs, const unsigned short* __restrict__ Wt,
    const float* __restrict__ bias,
    unsigned short* __restrict__ Qb, unsigned short* __restrict__ Kb,
    unsigned short* __restrict__ Vb)
{
    __shared__ __attribute__((aligned(16))) unsigned short As[128 * 32];
    __shared__ __attribute__((aligned(16))) unsigned short Bs[128 * 32];

    const int t = threadIdx.x;
    const int w = t >> 6, lane = t & 63, lr = lane & 15, lq = lane >> 4;
    const int wm = (w >> 1) * 64, wn = (w & 1) * 64;
    const int m0 = blockIdx.x * 128, n0 = blockIdx.y * 128;

    f32x4 acc[4][4];
    for (int mt = 0; mt < 4; mt++)
        for (int nt = 0; nt < 4; nt++)
            acc[mt][nt] = (f32x4){0.f, 0.f, 0.f, 0.f};

    for (int kt = 0; kt < E_; kt += 32) {
        __syncthreads();
        // B: async global->LDS (512 16B-chunks)
        for (int i = 0; i < 2; i++) {
            int c = t + i * 256;
            int row = c >> 2, kp = (c & 3) * 8;
            cp16(&Bs[c * 8], &Wt[(size_t)(n0 + row) * E_ + kt + kp]);
        }
        // A: fp32 -> bf16 reg-stage (1024 float4 chunks; banks conflict-free)
        for (int i = 0; i < 4; i++) {
            int c = t + i * 256;
            int row = c >> 3, k4 = (c & 7) * 4;
            float4 v = *reinterpret_cast<const float4*>(&Hs[(size_t)(m0 + row) * E_ + kt + k4]);
            uint2 o;
            o.x = cvt_pk(v.x, v.y);
            o.y = cvt_pk(v.z, v.w);
            *reinterpret_cast<uint2*>(&As[row * 32 + k4]) = o;
        }
        __syncthreads();
        bf16x8 af[4], bfr[4];
        for (int mt = 0; mt < 4; mt++) af[mt]  = ld_frag(&As[(wm + mt * 16 + lr) * 32 + lq * 8]);
        for (int nt = 0; nt < 4; nt++) bfr[nt] = ld_frag(&Bs[(wn + nt * 16 + lr) * 32 + lq * 8]);
        for (int mt = 0; mt < 4; mt++)
            for (int nt = 0; nt < 4; nt++)
                acc[mt][nt] = mfma16(af[mt], bfr[nt], acc[mt][nt]);
    }

    const int sector = (n0 >> 10);   // whole block maps to one of q/k/v (128 | 1024)
    for (int nt = 0; nt < 4; nt++) {
        int n = n0 + wn + nt * 16 + lr;
        float bv = bias[n];
        int nn = n & 1023, h = nn >> 6, d = nn & 63;
        for (int mt = 0; mt < 4; mt++) {
            for (int i = 0; i < 4; i++) {
                int tok = m0 + wm + mt * 16 + lq * 4 + i;
                int b = tok >> 11, s = tok & 2047;
                float v = acc[mt][nt][i] + bv;
                if (sector == 0) {
                    // fold 1/sqrt(D)=0.125 AND log2(e) into Q: attn uses exp2 directly
                    Qb[(((size_t)(b * H_ + h) * S_ + s) << 6) + d] = f2bf(v * 0.18033688f);
                } else if (sector == 1) {
                    Kb[(((size_t)(b * H_ + h) * S_ + s) << 6) + d] = f2bf(v);
                } else {
                    Vb[(((size_t)(b * H_ + h) * D_ + d) << 11) + s] = f2bf(v);  // V^T [B,H,D,S]
                }
            }
        }
    }
}

// ---------------- flash attention (no causal mask; no-max softmax, deferred l) ----------------
// 2-phase pipeline, 128-key macro-tiles (2x64 sub-tiles), dbuf K/V staging. Each wave owns
// 32 q-rows (two 16-row halves); K/V frags amortized over 2x MFMA. LDS = 80KB; grid 512 =
// 2 blocks/CU (grid-limited). All LDS surfaces dense with segment-XOR swizzle.
__global__ __launch_bounds__(256) void k_attn(
    const unsigned short* __restrict__ Qb, const unsigned short* __restrict__ Kb,
    const unsigned short* __restrict__ Vb, unsigned short* __restrict__ Ob)
{
    __shared__ __attribute__((aligned(16))) unsigned short Ks[2][128 * 64];  // [buf][key][d]
    __shared__ __attribute__((aligned(16))) unsigned short Vt[2][64 * 128];  // [buf][d][key]
    __shared__ __attribute__((aligned(16))) unsigned short Ps[4][32 * 64];   // per-wave P[q32][key64]

    const int t = threadIdx.x, w = t >> 6, lane = t & 63, lr = lane & 15, lq = lane >> 4;
    const int h = blockIdx.y, b = blockIdx.z;
    const size_t head = ((size_t)(b * H_ + h)) * (S_ * D_);
    const unsigned short* Qh = Qb + head;
    const unsigned short* Kh = Kb + head;
    const unsigned short* Vh = Vb + head;   // [D][S]
    const int q0 = blockIdx.x * 128 + w * 16;   // wave's q-halves: q0, q0+64
    const int swz = lr & 7;

    // Q fragments (B-operand): lane holds Q[q][d = kk*32 + lq*8 ..+8]; scale pre-folded
    bf16x8 qa[2][2];
    for (int qh = 0; qh < 2; qh++)
        for (int kk = 0; kk < 2; kk++)
            qa[qh][kk] = ld_frag(&Qh[(size_t)(q0 + qh * 64 + lr) * 64 + kk * 32 + lq * 8]);

    f32x4 o[2][4];
    for (int qh = 0; qh < 2; qh++)
        for (int i = 0; i < 4; i++) o[qh][i] = (f32x4){0.f, 0.f, 0.f, 0.f};
    float lsum[2] = {0.f, 0.f};
    unsigned short* Pw = Ps[w];

    // stage one 128-key tile into buffer bb:
    // K 128 rows x 8 segs of 16B (seg ^ row&7); V^T 64 rows x 16 segs (low-3-bit XOR by d)
    auto stage = [&](int bb, int kt) {
        for (int i = 0; i < 4; i++) {
            int c = t + i * 256;                          // 1024 chunks of 16B
            int row = c >> 3, sp = c & 7;
            cp16(&Ks[bb][c * 8], &Kh[(size_t)(kt + row) * 64 + (sp ^ (row & 7)) * 8]);
        }
        for (int i = 0; i < 4; i++) {
            int c = t + i * 256;
            int d = c >> 4, sp = c & 15, seg = (sp & 8) | ((sp & 7) ^ (d & 7));
            cp16(&Vt[bb][c * 8], &Vh[(size_t)d * S_ + kt + seg * 8]);
        }
    };

    stage(0, 0);
    asm volatile("s_waitcnt vmcnt(0)" ::: "memory");
    __syncthreads();

    int cur = 0;
#pragma unroll 2
    for (int kt = 0; kt < S_; kt += 128) {
        // issue next tile's loads first -- latency hides under this tile's compute
        if (kt + 128 < S_) stage(cur ^ 1, kt + 128);

        const unsigned short* Kc = Ks[cur];
        const unsigned short* Vc = Vt[cur];

#pragma unroll
        for (int ss = 0; ss < 2; ss++) {
            // scores: S^T[key][q], 4 key-tiles of 16 per sub-tile; K-frags reused across both
            // q-halves. lane reg r holds key = ss*64 + tau*16 + lq*4 + r, q = (qh*64)+lr
            for (int tau = 0; tau < 4; tau++) {
                int krow = ss * 64 + tau * 16 + lr;
                bf16x8 kf0 = ld_frag(&Kc[krow * 64 + ((0 + lq) ^ swz) * 8]);
                bf16x8 kf1 = ld_frag(&Kc[krow * 64 + ((4 + lq) ^ swz) * 8]);
                for (int qh = 0; qh < 2; qh++) {
                    f32x4 z = (f32x4){0.f, 0.f, 0.f, 0.f};
                    __builtin_amdgcn_s_setprio(1);
                    z = mfma16(kf0, qa[qh][0], z);
                    z = mfma16(kf1, qa[qh][1], z);
                    __builtin_amdgcn_s_setprio(0);
                    float e0 = __builtin_amdgcn_exp2f(z[0]);  // log2e folded into Q scale
                    float e1 = __builtin_amdgcn_exp2f(z[1]);
                    float e2 = __builtin_amdgcn_exp2f(z[2]);
                    float e3 = __builtin_amdgcn_exp2f(z[3]);
                    lsum[qh] += (e0 + e1) + (e2 + e3);
                    // P[q][key-within-subtile]: 4 consecutive keys -> one b64 write
                    uint2 pk;
                    pk.x = cvt_pk(e0, e1);
                    pk.y = cvt_pk(e2, e3);
                    int seg = (tau * 2 + (lq >> 1)) ^ swz;
                    *reinterpret_cast<uint2*>(&Pw[(qh * 16 + lr) * 64 + seg * 8 + (lq & 1) * 4]) = pk;
                }
            }
            // PV: O^T[d][q] += V^T * P^T ; A = Vt rows, B = P rows (wave-private, in-order DS).
            // V-frags reused across both q-halves.
            for (int kk = 0; kk < 2; kk++) {
                bf16x8 pf0 = ld_frag(&Pw[(lr) * 64 + ((kk * 4 + lq) ^ swz) * 8]);
                bf16x8 pf1 = ld_frag(&Pw[(16 + lr) * 64 + ((kk * 4 + lq) ^ swz) * 8]);
                __builtin_amdgcn_s_setprio(1);
                for (int t2 = 0; t2 < 4; t2++) {
                    int vrow = t2 * 16 + lr;
                    bf16x8 vf = ld_frag(&Vc[vrow * 128 + ((ss * 8) | ((kk * 4 + lq) ^ swz)) * 8]);
                    o[0][t2] = mfma16(vf, pf0, o[0][t2]);
                    o[1][t2] = mfma16(vf, pf1, o[1][t2]);
                }
                __builtin_amdgcn_s_setprio(0);
            }
        }

        // drain next-tile stage (hidden under compute) + single barrier per 128-key tile
        asm volatile("s_waitcnt vmcnt(0)" ::: "memory");
        __syncthreads();
        cur ^= 1;
    }

    // deferred softmax denominator: reduce across the 4 lq groups; then epilogue per q-half.
    for (int qh = 0; qh < 2; qh++) {
        float ls = lsum[qh];
        ls += __shfl_xor(ls, 16, 64);
        ls += __shfl_xor(ls, 32, 64);
        float inv = 1.0f / ls;

        // lane holds O^T[d = t2*16+lq*4+r][q = lr] -> Ob[(b,s)][h*64+d], b64 stores
        int s = q0 + qh * 64 + lr;
        size_t rowoff = ((size_t)(b * S_ + s)) * E_ + h * 64;
        for (int t2 = 0; t2 < 4; t2++) {
            uint2 pk;
            pk.x = cvt_pk(o[qh][t2][0] * inv, o[qh][t2][1] * inv);
            pk.y = cvt_pk(o[qh][t2][2] * inv, o[qh][t2][3] * inv);
            *reinterpret_cast<uint2*>(&Ob[rowoff + t2 * 16 + lq * 4]) = pk;
        }
    }
}

// ---------------- output projection + bias -> fp32 out ----------------
// R3-exact: 128x64 tile (512 blocks = 2/CU), BK=32, 2-barrier schedule.
__global__ __launch_bounds__(256) void k_proj(
    const unsigned short* __restrict__ Ab, const unsigned short* __restrict__ Wt,
    const float* __restrict__ bias, float* __restrict__ out)
{
    __shared__ __attribute__((aligned(16))) unsigned short As[128 * 32];
    __shared__ __attribute__((aligned(16))) unsigned short Bs[64 * 32];
    const int t = threadIdx.x;
    const int w = t >> 6, lane = t & 63, lr = lane & 15, lq = lane >> 4;
    const int wm = (w >> 1) * 64, wn = (w & 1) * 32;
    const int m0 = blockIdx.x * 128, n0 = blockIdx.y * 64;

    f32x4 acc[4][2];
    for (int mt = 0; mt < 4; mt++)
        for (int nt = 0; nt < 2; nt++)
            acc[mt][nt] = (f32x4){0.f, 0.f, 0.f, 0.f};

    for (int kt = 0; kt < E_; kt += 32) {
        __syncthreads();
        for (int i = 0; i < 2; i++) {
            int c = t + i * 256;          // A: 512 16B-chunks
            int row = c >> 2, kp = (c & 3) * 8;
            cp16(&As[c * 8], &Ab[(size_t)(m0 + row) * E_ + kt + kp]);
        }
        {
            int c = t;                    // B: 256 16B-chunks
            int row = c >> 2, kp = (c & 3) * 8;
            cp16(&Bs[c * 8], &Wt[(size_t)(n0 + row) * E_ + kt + kp]);
        }
        __syncthreads();
        bf16x8 af[4], bfr[2];
        for (int mt = 0; mt < 4; mt++) af[mt]  = ld_frag(&As[(wm + mt * 16 + lr) * 32 + lq * 8]);
        for (int nt = 0; nt < 2; nt++) bfr[nt] = ld_frag(&Bs[(wn + nt * 16 + lr) * 32 + lq * 8]);
        for (int mt = 0; mt < 4; mt++)
            for (int nt = 0; nt < 2; nt++)
                acc[mt][nt] = mfma16(af[mt], bfr[nt], acc[mt][nt]);
    }

    for (int nt = 0; nt < 2; nt++) {
        int n = n0 + wn + nt * 16 + lr;
        float bv = bias[n];
        for (int mt = 0; mt < 4; mt++)
            for (int i = 0; i < 4; i++) {
                int tok = m0 + wm + mt * 16 + lq * 4 + i;
                out[(size_t)tok * E_ + n] = acc[mt][nt][i] + bv;
            }
    }
}

extern "C" void kernel_launch(void* const* d_in, const int* in_sizes, int n_in,
                              void* d_out, int out_size, void* d_ws, size_t ws_size,
                              hipStream_t stream) {
    const float* hs = (const float*)d_in[0];   // [2,2048,1024]
    const float* w1 = (const float*)d_in[1];   // [1024,3072]
    const float* b1 = (const float*)d_in[2];   // [3072]
    const float* w2 = (const float*)d_in[3];   // [1024,1024]
    const float* b2 = (const float*)d_in[4];   // [1024]
    float* out = (float*)d_out;

    char* ws = (char*)d_ws;
    unsigned short* w1t = (unsigned short*)(ws + (size_t)( 8 << 20));  // 6 MB W_qkv^T bf16
    unsigned short* w2t = (unsigned short*)(ws + (size_t)(14 << 20));  // 2 MB W_proj^T bf16
    unsigned short* Qb  = (unsigned short*)(ws + (size_t)(16 << 20));  // 8 MB [B,H,S,D] (pre-scaled)
    unsigned short* Kb  = (unsigned short*)(ws + (size_t)(24 << 20));  // 8 MB [B,H,S,D]
    unsigned short* Vb  = (unsigned short*)(ws + (size_t)(32 << 20));  // 8 MB [B,H,D,S]
    unsigned short* Ao  = (unsigned short*)(ws + (size_t)(40 << 20));  // 8 MB [T,E]

    k_wt2<<<dim3(128, 32), dim3(32, 8), 0, stream>>>(w1, w1t, w2, w2t);
    k_qkv<<<dim3(T_ / 128, NQ_ / 128), dim3(256), 0, stream>>>(hs, w1t, b1, Qb, Kb, Vb);
    k_attn<<<dim3(S_ / 128, H_, B_), dim3(256), 0, stream>>>(Qb, Kb, Vb, Ao);
    k_proj<<<dim3(T_ / 128, E_ / 64), dim3(256), 0, stream>>>(Ao, w2t, b2, out);
}